// Round 3
// baseline (228.123 us; speedup 1.0000x reference)
//
#include <hip/hip_runtime.h>
#include <hip/hip_bf16.h>
#include <hip/hip_cooperative_groups.h>

namespace cg = cooperative_groups;

// BilinearPooling: out[i,k] = mean_j(conv1[i,j]) * conv2[i,k]
// B=256, J=K=14*14*256=50176.
//
// R2 post-mortem: two-kernel split made each dispatch fast but end-to-end was
// flat — second launch + inter-kernel gap ate the gain. R3: single cooperative
// kernel, grid-wide sync between reduce and scale phases.
//
// Grid 2048 x 256 = 8192 waves = 32 waves/CU exactly co-resident
// (12 VGPR, 512 B LDS -> no occupancy limiter).

#define NROWS     256
#define ROW_ELEMS 50176           // 14*14*256
#define ROW_VEC   (ROW_ELEMS/4)   // 12544 float4 per row
#define SEGS      8
#define SEG_VEC   (ROW_VEC/SEGS)  // 1568 float4 per segment
#define THREADS   256
#define GRID      (NROWS*SEGS)    // 2048 blocks

__global__ __launch_bounds__(THREADS)
void bp_fused_kernel(const float4* __restrict__ c1,
                     const float4* __restrict__ c2,
                     float4* __restrict__ out,
                     float* __restrict__ partials) {
    const int row = blockIdx.x >> 3;          // / SEGS
    const int seg = blockIdx.x & (SEGS - 1);
    const size_t base = (size_t)row * ROW_VEC + (size_t)seg * SEG_VEC;

    // ---- Phase 1: partial sum of this conv1 segment ----
    float s = 0.0f;
    for (int i = threadIdx.x; i < SEG_VEC; i += THREADS) {
        float4 v = c1[base + i];
        s += (v.x + v.y) + (v.z + v.w);
    }

    #pragma unroll
    for (int off = 32; off > 0; off >>= 1)
        s += __shfl_down(s, off, 64);

    __shared__ float wsum[THREADS / 64];
    const int lane = threadIdx.x & 63;
    const int wid  = threadIdx.x >> 6;
    if (lane == 0) wsum[wid] = s;
    __syncthreads();
    if (threadIdx.x == 0) {
        float t = 0.0f;
        #pragma unroll
        for (int i = 0; i < THREADS / 64; ++i) t += wsum[i];
        partials[blockIdx.x] = t;
    }

    // ---- Grid-wide barrier ----
    cg::this_grid().sync();

    // ---- Phase 2: scale conv2 segment by row mean ----
    float t = 0.0f;
    #pragma unroll
    for (int i = 0; i < SEGS; ++i)
        t += partials[(row << 3) + i];        // wave-uniform, L2-hot
    const float m = t * (1.0f / (float)ROW_ELEMS);

    for (int i = threadIdx.x; i < SEG_VEC; i += THREADS) {
        float4 v = c2[base + i];
        v.x *= m; v.y *= m; v.z *= m; v.w *= m;
        out[base + i] = v;
    }
}

extern "C" void kernel_launch(void* const* d_in, const int* in_sizes, int n_in,
                              void* d_out, int out_size, void* d_ws, size_t ws_size,
                              hipStream_t stream) {
    const float4* c1 = (const float4*)d_in[0];
    const float4* c2 = (const float4*)d_in[1];
    float4* out = (float4*)d_out;
    float* partials = (float*)d_ws;           // GRID floats = 8 KB

    void* args[] = { (void*)&c1, (void*)&c2, (void*)&out, (void*)&partials };
    hipLaunchCooperativeKernel((void*)bp_fused_kernel,
                               dim3(GRID), dim3(THREADS),
                               args, 0, stream);
}

// Round 4
// 200.578 us; speedup vs baseline: 1.1373x; 1.1373x over previous
//
#include <hip/hip_runtime.h>
#include <hip/hip_bf16.h>

// BilinearPooling: out[i,k] = mean_j(conv1[i,j]) * conv2[i,k]
// B=256, J=K=14*14*256=50176.
//
// R3 post-mortem: cg::this_grid().sync() cost ~80 us (2048 blocks spinning on
// one device-scope counter across 8 non-coherent XCD L2s). R4: same fused
// single-launch structure, but per-ROW sync: 8 blocks/row publish partials
// with release-tagged flags, spin-acquire on just their row's 8 flags.
// Harness poisons ws to 0xAAAAAAAA != 1, so tags need no zeroing.
// Cooperative launch guarantees co-residency (2048 blocks x 4 waves
// = 32 waves/CU exactly) -> spin is deadlock-free.

#define NROWS     256
#define ROW_ELEMS 50176           // 14*14*256
#define ROW_VEC   (ROW_ELEMS/4)   // 12544 float4 per row
#define SEGS      8
#define SEG_VEC   (ROW_VEC/SEGS)  // 1568 float4 per segment
#define THREADS   256
#define GRID      (NROWS*SEGS)    // 2048 blocks

__global__ __launch_bounds__(THREADS)
void bp_fused_kernel(const float4* __restrict__ c1,
                     const float4* __restrict__ c2,
                     float4* __restrict__ out,
                     float* __restrict__ partials,
                     unsigned* __restrict__ tags) {
    const int row = blockIdx.x >> 3;          // / SEGS
    const int seg = blockIdx.x & (SEGS - 1);
    const size_t base = (size_t)row * ROW_VEC + (size_t)seg * SEG_VEC;

    // ---- Phase 1: partial sum of this conv1 segment ----
    float s = 0.0f;
    for (int i = threadIdx.x; i < SEG_VEC; i += THREADS) {
        float4 v = c1[base + i];
        s += (v.x + v.y) + (v.z + v.w);
    }

    #pragma unroll
    for (int off = 32; off > 0; off >>= 1)
        s += __shfl_down(s, off, 64);

    __shared__ float wsum[THREADS / 64];
    __shared__ float rowpart[SEGS];
    const int lane = threadIdx.x & 63;
    const int wid  = threadIdx.x >> 6;
    if (lane == 0) wsum[wid] = s;
    __syncthreads();
    if (threadIdx.x == 0) {
        float t = (wsum[0] + wsum[1]) + (wsum[2] + wsum[3]);
        __hip_atomic_store(&partials[blockIdx.x], t,
                           __ATOMIC_RELAXED, __HIP_MEMORY_SCOPE_AGENT);
        __hip_atomic_store(&tags[blockIdx.x], 1u,
                           __ATOMIC_RELEASE, __HIP_MEMORY_SCOPE_AGENT);
    }

    // ---- Per-row sync: wait for this row's 8 partials ----
    if (threadIdx.x < SEGS) {
        const int idx = (row << 3) + threadIdx.x;
        while (__hip_atomic_load(&tags[idx],
                                 __ATOMIC_ACQUIRE, __HIP_MEMORY_SCOPE_AGENT) != 1u)
            __builtin_amdgcn_s_sleep(1);
        rowpart[threadIdx.x] =
            __hip_atomic_load(&partials[idx],
                              __ATOMIC_RELAXED, __HIP_MEMORY_SCOPE_AGENT);
    }
    __syncthreads();

    const float m = (((rowpart[0] + rowpart[1]) + (rowpart[2] + rowpart[3])) +
                     ((rowpart[4] + rowpart[5]) + (rowpart[6] + rowpart[7]))) *
                    (1.0f / (float)ROW_ELEMS);

    // ---- Phase 2: scale conv2 segment by row mean ----
    for (int i = threadIdx.x; i < SEG_VEC; i += THREADS) {
        float4 v = c2[base + i];
        v.x *= m; v.y *= m; v.z *= m; v.w *= m;
        out[base + i] = v;
    }
}

extern "C" void kernel_launch(void* const* d_in, const int* in_sizes, int n_in,
                              void* d_out, int out_size, void* d_ws, size_t ws_size,
                              hipStream_t stream) {
    const float4* c1 = (const float4*)d_in[0];
    const float4* c2 = (const float4*)d_in[1];
    float4* out = (float4*)d_out;
    float* partials = (float*)d_ws;                  // 2048 floats
    unsigned* tags  = (unsigned*)d_ws + GRID;        // 2048 uints (poison != 1)

    void* args[] = { (void*)&c1, (void*)&c2, (void*)&out,
                     (void*)&partials, (void*)&tags };
    hipLaunchCooperativeKernel((void*)bp_fused_kernel,
                               dim3(GRID), dim3(THREADS),
                               args, 0, stream);
}

// Round 6
// 139.521 us; speedup vs baseline: 1.6350x; 1.4376x over previous
//
#include <hip/hip_runtime.h>
#include <hip/hip_bf16.h>

// BilinearPooling: out[i,k] = mean_j(conv1[i,j]) * conv2[i,k]
// B=256, J=K=14*14*256=50176.
//
// R3/R4 post-mortem: ANY cross-block dependency (grid.sync: +80us,
// per-row release/acquire flags: +50us) collapses BW on this chip — the
// XCD coherence round-trips dominate. R5/R6: redundant computation instead
// of communication. 2 blocks per row; EACH block reduces the full conv1 row
// (200 KB, second reader hits L2/L3) and computes the mean independently,
// then scales its own half of the conv2 row. Zero cross-block traffic,
// single launch, only intra-block __syncthreads.
// Grid 512 x 1024 thr = 8192 waves = 32 waves/CU exactly.
//
// R6 fix: __builtin_nontemporal_* rejects HIP_vector_type -> use clang
// ext_vector_type(4) float for the streamed accesses.

#define NROWS     256
#define ROW_ELEMS 50176           // 14*14*256
#define ROW_VEC   (ROW_ELEMS/4)   // 12544 float4 per row
#define HALF_VEC  (ROW_VEC/2)     // 6272 float4 per half-row
#define THREADS   1024

typedef float vfloat4 __attribute__((ext_vector_type(4)));

__global__ __launch_bounds__(THREADS)
void bp_fused_kernel(const vfloat4* __restrict__ c1,
                     const vfloat4* __restrict__ c2,
                     vfloat4* __restrict__ out) {
    const int row  = blockIdx.x >> 1;
    const int half = blockIdx.x & 1;

    // ---- Phase 1: full-row reduction of conv1 (redundant per half) ----
    const vfloat4* __restrict__ r1 = c1 + (size_t)row * ROW_VEC;
    float s = 0.0f;
    for (int i = threadIdx.x; i < ROW_VEC; i += THREADS) {
        vfloat4 v = r1[i];
        s += (v.x + v.y) + (v.z + v.w);
    }

    #pragma unroll
    for (int off = 32; off > 0; off >>= 1)
        s += __shfl_down(s, off, 64);

    __shared__ float wsum[THREADS / 64];
    __shared__ float mean_s;
    const int lane = threadIdx.x & 63;
    const int wid  = threadIdx.x >> 6;
    if (lane == 0) wsum[wid] = s;
    __syncthreads();
    if (threadIdx.x == 0) {
        float t = 0.0f;
        #pragma unroll
        for (int i = 0; i < THREADS / 64; ++i) t += wsum[i];
        mean_s = t * (1.0f / (float)ROW_ELEMS);
    }
    __syncthreads();
    const float m = mean_s;

    // ---- Phase 2: scale this block's half of the conv2 row ----
    const size_t base = (size_t)row * ROW_VEC + (size_t)half * HALF_VEC;
    const vfloat4* __restrict__ r2 = c2 + base;
    vfloat4* __restrict__ ro = out + base;
    for (int i = threadIdx.x; i < HALF_VEC; i += THREADS) {
        vfloat4 v = __builtin_nontemporal_load(&r2[i]);
        v.x *= m; v.y *= m; v.z *= m; v.w *= m;
        __builtin_nontemporal_store(v, &ro[i]);
    }
}

extern "C" void kernel_launch(void* const* d_in, const int* in_sizes, int n_in,
                              void* d_out, int out_size, void* d_ws, size_t ws_size,
                              hipStream_t stream) {
    const vfloat4* c1 = (const vfloat4*)d_in[0];
    const vfloat4* c2 = (const vfloat4*)d_in[1];
    vfloat4* out = (vfloat4*)d_out;

    bp_fused_kernel<<<NROWS * 2, THREADS, 0, stream>>>(c1, c2, out);
}